// Round 1
// baseline (162.697 us; speedup 1.0000x reference)
//
#include <hip/hip_runtime.h>
#include <cmath>

#define NEG_INF (-1.0e30f)

static constexpr int B = 256;
static constexpr int N = 65536;
static constexpr int THREADS = 1024;
static constexpr int SPLIT = 2;              // blocks per row
static constexpr float C_OFF = 40.96f;       // = 64 * 0.8^2, upper bound of both logits

__device__ __forceinline__ float wave_sum_f(float v) {
#pragma unroll
  for (int off = 32; off >= 1; off >>= 1) v += __shfl_xor(v, off, 64);
  return v;
}
__device__ __forceinline__ int wave_sum_i(int v) {
#pragma unroll
  for (int off = 32; off >= 1; off >>= 1) v += __shfl_xor(v, off, 64);
  return v;
}

// Merge this lane's descending-sorted 16-list with XOR-partner lane's list,
// keeping the top-16 of the union (bitonic top-k merge).
__device__ __forceinline__ void merge_lists_shfl(float t[16], int off) {
  float b[16];
#pragma unroll
  for (int i = 0; i < 16; ++i) b[i] = __shfl_xor(t[i], off, 64);
  float c[16];
#pragma unroll
  for (int i = 0; i < 16; ++i) c[i] = fmaxf(t[i], b[15 - i]);
#pragma unroll
  for (int s = 8; s >= 1; s >>= 1) {
#pragma unroll
    for (int i = 0; i < 16; ++i) {
      if ((i & s) == 0) {
        float lo = c[i], hi = c[i + s];
        c[i] = fmaxf(lo, hi);
        c[i + s] = fminf(lo, hi);
      }
    }
  }
#pragma unroll
  for (int i = 0; i < 16; ++i) t[i] = c[i];
}

// Same top-16 merge, but between two register lists (no shuffle).
__device__ __forceinline__ void merge_lists_local(float a[16], const float b[16]) {
  float c[16];
#pragma unroll
  for (int i = 0; i < 16; ++i) c[i] = fmaxf(a[i], b[15 - i]);
#pragma unroll
  for (int s = 8; s >= 1; s >>= 1) {
#pragma unroll
    for (int i = 0; i < 16; ++i) {
      if ((i & s) == 0) {
        float lo = c[i], hi = c[i + s];
        c[i] = fmaxf(lo, hi);
        c[i + s] = fminf(lo, hi);
      }
    }
  }
#pragma unroll
  for (int i = 0; i < 16; ++i) a[i] = c[i];
}

__device__ __forceinline__ void process_elem(float s, float l, float& s_p,
                                             float& s_n, int& nn, float t[16]) {
  const bool pos = l > 0.5f;
  const bool neg = l < 0.25f;
  // logit_p = 64*relu(0.8-s)^2 ; logit_n = 64*relu(s-0.2)^2 (both in [0, 40.96])
  float d = pos ? (0.8f - s) : (s - 0.2f);
  float r = fmaxf(d, 0.f);
  float arg = __builtin_fmaf(64.f * r, r, -C_OFF);  // <= 0, finite for all s
  float e = __expf(arg);
  if (pos) s_p += e;
  if (neg) {
    s_n += e;
    ++nn;
    if (s > t[9]) {  // maintain sorted-descending top-10 (t[10..15] stay pad)
      t[9] = s;
#pragma unroll
      for (int i = 9; i > 0; --i) {
        float a = t[i - 1], bb = t[i];
        t[i - 1] = fmaxf(a, bb);
        t[i] = fminf(a, bb);
      }
    }
  }
}

// One block per (row, half). Writes partial {sum_p, sum_n, count_n, top16} to ws.
__global__ void __launch_bounds__(THREADS, 8) ranking_partial_kernel(
    const float* __restrict__ sim, const float* __restrict__ label,
    float* __restrict__ ws_sp, float* __restrict__ ws_sn,
    int* __restrict__ ws_cnt, float* __restrict__ ws_top) {
  const int blk = blockIdx.x;
  const int row = blk >> 1;  // SPLIT == 2
  const int half = blk & 1;
  const int tid = threadIdx.x;
  const size_t base4 = (size_t)row * (N / 4) + (size_t)half * (N / (4 * SPLIT));
  const float4* sim4 = reinterpret_cast<const float4*>(sim) + base4;
  const float4* lab4 = reinterpret_cast<const float4*>(label) + base4;

  float s_p = 0.f, s_n = 0.f;
  int nn = 0;
  float t[16];
#pragma unroll
  for (int i = 0; i < 16; ++i) t[i] = NEG_INF;

  constexpr int ITER = N / 4 / THREADS / SPLIT;  // 8
#pragma unroll
  for (int it = 0; it < ITER; ++it) {
    float4 sv = sim4[it * THREADS + tid];
    float4 lv = lab4[it * THREADS + tid];
    process_elem(sv.x, lv.x, s_p, s_n, nn, t);
    process_elem(sv.y, lv.y, s_p, s_n, nn, t);
    process_elem(sv.z, lv.z, s_p, s_n, nn, t);
    process_elem(sv.w, lv.w, s_p, s_n, nn, t);
  }

  // intra-wave reductions
  s_p = wave_sum_f(s_p);
  s_n = wave_sum_f(s_n);
  nn = wave_sum_i(nn);
#pragma unroll
  for (int off = 1; off < 64; off <<= 1) merge_lists_shfl(t, off);

  __shared__ float ls_p[16], ls_n[16];
  __shared__ int ls_c[16];
  __shared__ float ltop[16][16];
  const int wave = tid >> 6, lane = tid & 63;
  if (lane == 0) {
    ls_p[wave] = s_p;
    ls_n[wave] = s_n;
    ls_c[wave] = nn;
#pragma unroll
    for (int i = 0; i < 16; ++i) ltop[wave][i] = t[i];
  }
  __syncthreads();

  if (wave == 0) {
    // lanes 0..15 each hold one wave's top-16; butterfly-merge them
    float m[16];
    if (lane < 16) {
#pragma unroll
      for (int i = 0; i < 16; ++i) m[i] = ltop[lane][i];
    } else {
#pragma unroll
      for (int i = 0; i < 16; ++i) m[i] = NEG_INF;
    }
    merge_lists_shfl(m, 1);
    merge_lists_shfl(m, 2);
    merge_lists_shfl(m, 4);
    merge_lists_shfl(m, 8);

    float sp = (lane < 16) ? ls_p[lane] : 0.f;
    float sn = (lane < 16) ? ls_n[lane] : 0.f;
    int cn = (lane < 16) ? ls_c[lane] : 0;
    sp = wave_sum_f(sp);
    sn = wave_sum_f(sn);
    cn = wave_sum_i(cn);

    if (lane == 0) {
      ws_sp[blk] = sp;
      ws_sn[blk] = sn;
      ws_cnt[blk] = cn;
#pragma unroll
      for (int i = 0; i < 16; ++i) ws_top[blk * 16 + i] = m[i];
    }
  }
}

// One block, 256 threads: thread r combines the two halves of row r,
// computes the row loss, then the block reduces to the final mean.
__global__ void __launch_bounds__(256) combine_kernel(
    const float* __restrict__ ws_sp, const float* __restrict__ ws_sn,
    const int* __restrict__ ws_cnt, const float* __restrict__ ws_top,
    float* __restrict__ out) {
  const int r = threadIdx.x;
  const int p0 = r * 2, p1 = r * 2 + 1;

  float a[16], b[16];
#pragma unroll
  for (int i = 0; i < 16; ++i) a[i] = ws_top[p0 * 16 + i];
#pragma unroll
  for (int i = 0; i < 16; ++i) b[i] = ws_top[p1 * 16 + i];
  merge_lists_local(a, b);  // a = top-16 of the row, sorted descending

  float sp = ws_sp[p0] + ws_sp[p1];
  float sn = ws_sn[p0] + ws_sn[p1];
  int cn = ws_cnt[p0] + ws_cnt[p1];

  // any positives <=> sp > 0 (each pos term >= exp(-40.96) > 0)
  float lse_p = (sp > 0.f) ? (C_OFF + __logf(sp)) : 0.f;
  float lse_n_all = (sn > 0.f) ? (C_OFF + __logf(sn)) : NEG_INF;

  // top-10 logsumexp (a[0..9] = top-10 negative sims; pad -1e30 -> logit -0)
  float mx = NEG_INF;
  float lg[10];
#pragma unroll
  for (int i = 0; i < 10; ++i) {
    float v = a[i];
    float al = fmaxf(v - 0.2f, 0.f);
    float lo = al * (v - 0.2f) * 64.f;
    lg[i] = lo;
    mx = fmaxf(mx, lo);
  }
  float ss = 0.f;
#pragma unroll
  for (int i = 0; i < 10; ++i) ss += __expf(lg[i] - mx);
  float lse_n_top = mx + __logf(ss);

  float lse_n = (cn > 20) ? lse_n_top : lse_n_all;
  float x = lse_n + lse_p;
  // softplus(x) = max(x,0) + log1p(exp(-|x|))
  float loss = fmaxf(x, 0.f) + log1pf(__expf(-fabsf(x)));

  // block reduction (256 threads = 4 waves)
  float v = wave_sum_f(loss);
  __shared__ float wsh[4];
  if ((r & 63) == 0) wsh[r >> 6] = v;
  __syncthreads();
  if (r == 0) out[0] = (wsh[0] + wsh[1] + wsh[2] + wsh[3]) * (1.0f / 256.0f);
}

extern "C" void kernel_launch(void* const* d_in, const int* in_sizes, int n_in,
                              void* d_out, int out_size, void* d_ws, size_t ws_size,
                              hipStream_t stream) {
  const float* sim = (const float*)d_in[0];
  const float* label = (const float*)d_in[1];
  float* out = (float*)d_out;

  // workspace layout (floats): sp[512] | sn[512] | top[512*16] | cnt[512]
  float* wsf = (float*)d_ws;
  float* ws_sp = wsf;
  float* ws_sn = wsf + 512;
  float* ws_top = wsf + 1024;
  int* ws_cnt = (int*)(wsf + 1024 + 512 * 16);

  ranking_partial_kernel<<<dim3(B * SPLIT), dim3(THREADS), 0, stream>>>(
      sim, label, ws_sp, ws_sn, ws_cnt, ws_top);
  combine_kernel<<<dim3(1), dim3(256), 0, stream>>>(ws_sp, ws_sn, ws_cnt, ws_top,
                                                    out);
}

// Round 2
// 161.470 us; speedup vs baseline: 1.0076x; 1.0076x over previous
//
#include <hip/hip_runtime.h>
#include <cmath>

#define NEG_INF (-1.0e30f)

static constexpr int B = 256;
static constexpr int N = 65536;
static constexpr int THREADS = 256;          // 4 waves/block
static constexpr int SPLIT = 4;              // blocks per row -> grid = 1024
static constexpr float C_OFF = 40.96f;       // = 64 * 0.8^2, upper bound of both logits

__device__ __forceinline__ float wave_sum_f(float v) {
#pragma unroll
  for (int off = 32; off >= 1; off >>= 1) v += __shfl_xor(v, off, 64);
  return v;
}
__device__ __forceinline__ int wave_sum_i(int v) {
#pragma unroll
  for (int off = 32; off >= 1; off >>= 1) v += __shfl_xor(v, off, 64);
  return v;
}

// Merge this lane's descending-sorted 16-list with XOR-partner lane's list,
// keeping the top-16 of the union (bitonic top-k merge).
__device__ __forceinline__ void merge_lists_shfl(float t[16], int off) {
  float b[16];
#pragma unroll
  for (int i = 0; i < 16; ++i) b[i] = __shfl_xor(t[i], off, 64);
  float c[16];
#pragma unroll
  for (int i = 0; i < 16; ++i) c[i] = fmaxf(t[i], b[15 - i]);
#pragma unroll
  for (int s = 8; s >= 1; s >>= 1) {
#pragma unroll
    for (int i = 0; i < 16; ++i) {
      if ((i & s) == 0) {
        float lo = c[i], hi = c[i + s];
        c[i] = fmaxf(lo, hi);
        c[i + s] = fminf(lo, hi);
      }
    }
  }
#pragma unroll
  for (int i = 0; i < 16; ++i) t[i] = c[i];
}

// Same top-16 merge, but between two register lists (no shuffle).
__device__ __forceinline__ void merge_lists_local(float a[16], const float b[16]) {
  float c[16];
#pragma unroll
  for (int i = 0; i < 16; ++i) c[i] = fmaxf(a[i], b[15 - i]);
#pragma unroll
  for (int s = 8; s >= 1; s >>= 1) {
#pragma unroll
    for (int i = 0; i < 16; ++i) {
      if ((i & s) == 0) {
        float lo = c[i], hi = c[i + s];
        c[i] = fmaxf(lo, hi);
        c[i + s] = fminf(lo, hi);
      }
    }
  }
#pragma unroll
  for (int i = 0; i < 16; ++i) a[i] = c[i];
}

__device__ __forceinline__ void process_elem(float s, float l, float& s_p,
                                             float& s_n, int& nn, float t[16]) {
  const bool pos = l > 0.5f;
  const bool neg = l < 0.25f;
  // logit_p = 64*relu(0.8-s)^2 ; logit_n = 64*relu(s-0.2)^2 (both in [0, 40.96])
  float d = pos ? (0.8f - s) : (s - 0.2f);
  float r = fmaxf(d, 0.f);
  float arg = __builtin_fmaf(64.f * r, r, -C_OFF);  // <= 0, finite for all s
  float e = __expf(arg);
  if (pos) s_p += e;
  if (neg) {
    s_n += e;
    ++nn;
    if (s > t[9]) {  // maintain sorted-descending top-10 (t[10..15] stay pad)
      t[9] = s;
#pragma unroll
      for (int i = 9; i > 0; --i) {
        float a = t[i - 1], bb = t[i];
        t[i - 1] = fmaxf(a, bb);
        t[i] = fminf(a, bb);
      }
    }
  }
}

// One block per (row, quarter). Writes partial {sum_p, sum_n, count_n, top16}.
__global__ void __launch_bounds__(THREADS, 4) ranking_partial_kernel(
    const float* __restrict__ sim, const float* __restrict__ label,
    float* __restrict__ ws_sp, float* __restrict__ ws_sn,
    int* __restrict__ ws_cnt, float* __restrict__ ws_top) {
  const int blk = blockIdx.x;
  const int row = blk >> 2;  // SPLIT == 4
  const int part = blk & 3;
  const int tid = threadIdx.x;
  const size_t base4 = (size_t)row * (N / 4) + (size_t)part * (N / (4 * SPLIT));
  const float4* sim4 = reinterpret_cast<const float4*>(sim) + base4;
  const float4* lab4 = reinterpret_cast<const float4*>(label) + base4;

  float s_p = 0.f, s_n = 0.f;
  int nn = 0;
  float t[16];
#pragma unroll
  for (int i = 0; i < 16; ++i) t[i] = NEG_INF;

  constexpr int ITER = N / 4 / THREADS / SPLIT;  // 16
  // Hand-pipelined: batch 4 iterations of loads (8 dwordx4 in flight), then
  // process. Full unroll keeps all indexing compile-time (registers, no
  // scratch) and lets the scheduler prefetch the next group during compute.
#pragma unroll
  for (int it = 0; it < ITER; it += 4) {
    float4 sv[4], lv[4];
#pragma unroll
    for (int j = 0; j < 4; ++j) {
      sv[j] = sim4[(it + j) * THREADS + tid];
      lv[j] = lab4[(it + j) * THREADS + tid];
    }
#pragma unroll
    for (int j = 0; j < 4; ++j) {
      process_elem(sv[j].x, lv[j].x, s_p, s_n, nn, t);
      process_elem(sv[j].y, lv[j].y, s_p, s_n, nn, t);
      process_elem(sv[j].z, lv[j].z, s_p, s_n, nn, t);
      process_elem(sv[j].w, lv[j].w, s_p, s_n, nn, t);
    }
  }

  // intra-wave reductions
  s_p = wave_sum_f(s_p);
  s_n = wave_sum_f(s_n);
  nn = wave_sum_i(nn);
#pragma unroll
  for (int off = 1; off < 64; off <<= 1) merge_lists_shfl(t, off);

  __shared__ float ls_p[4], ls_n[4];
  __shared__ int ls_c[4];
  __shared__ float ltop[4][16];
  const int wave = tid >> 6, lane = tid & 63;
  if (lane == 0) {
    ls_p[wave] = s_p;
    ls_n[wave] = s_n;
    ls_c[wave] = nn;
#pragma unroll
    for (int i = 0; i < 16; ++i) ltop[wave][i] = t[i];
  }
  __syncthreads();

  if (wave == 0) {
    // lanes 0..3 each hold one wave's top-16; butterfly-merge them
    float m[16];
    if (lane < 4) {
#pragma unroll
      for (int i = 0; i < 16; ++i) m[i] = ltop[lane][i];
    } else {
#pragma unroll
      for (int i = 0; i < 16; ++i) m[i] = NEG_INF;
    }
    merge_lists_shfl(m, 1);
    merge_lists_shfl(m, 2);

    float sp = (lane < 4) ? ls_p[lane] : 0.f;
    float sn = (lane < 4) ? ls_n[lane] : 0.f;
    int cn = (lane < 4) ? ls_c[lane] : 0;
    sp = wave_sum_f(sp);
    sn = wave_sum_f(sn);
    cn = wave_sum_i(cn);

    if (lane == 0) {
      ws_sp[blk] = sp;
      ws_sn[blk] = sn;
      ws_cnt[blk] = cn;
#pragma unroll
      for (int i = 0; i < 16; ++i) ws_top[blk * 16 + i] = m[i];
    }
  }
}

// One block, 256 threads: thread r combines the SPLIT partials of row r,
// computes the row loss, then the block reduces to the final mean.
__global__ void __launch_bounds__(256) combine_kernel(
    const float* __restrict__ ws_sp, const float* __restrict__ ws_sn,
    const int* __restrict__ ws_cnt, const float* __restrict__ ws_top,
    float* __restrict__ out) {
  const int r = threadIdx.x;
  const int p0 = r * SPLIT;

  float a[16];
#pragma unroll
  for (int i = 0; i < 16; ++i) a[i] = ws_top[p0 * 16 + i];
#pragma unroll
  for (int k = 1; k < SPLIT; ++k) {
    float b[16];
#pragma unroll
    for (int i = 0; i < 16; ++i) b[i] = ws_top[(p0 + k) * 16 + i];
    merge_lists_local(a, b);  // a = running top-16, sorted descending
  }

  float sp = 0.f, sn = 0.f;
  int cn = 0;
#pragma unroll
  for (int k = 0; k < SPLIT; ++k) {
    sp += ws_sp[p0 + k];
    sn += ws_sn[p0 + k];
    cn += ws_cnt[p0 + k];
  }

  // any positives <=> sp > 0 (each pos term >= exp(-40.96) > 0)
  float lse_p = (sp > 0.f) ? (C_OFF + __logf(sp)) : 0.f;
  float lse_n_all = (sn > 0.f) ? (C_OFF + __logf(sn)) : NEG_INF;

  // top-10 logsumexp (a[0..9] = top-10 negative sims; pad -1e30 -> logit -0)
  float mx = NEG_INF;
  float lg[10];
#pragma unroll
  for (int i = 0; i < 10; ++i) {
    float v = a[i];
    float al = fmaxf(v - 0.2f, 0.f);
    float lo = al * (v - 0.2f) * 64.f;
    lg[i] = lo;
    mx = fmaxf(mx, lo);
  }
  float ss = 0.f;
#pragma unroll
  for (int i = 0; i < 10; ++i) ss += __expf(lg[i] - mx);
  float lse_n_top = mx + __logf(ss);

  float lse_n = (cn > 20) ? lse_n_top : lse_n_all;
  float x = lse_n + lse_p;
  // softplus(x) = max(x,0) + log1p(exp(-|x|))
  float loss = fmaxf(x, 0.f) + log1pf(__expf(-fabsf(x)));

  // block reduction (256 threads = 4 waves)
  float v = wave_sum_f(loss);
  __shared__ float wsh[4];
  if ((r & 63) == 0) wsh[r >> 6] = v;
  __syncthreads();
  if (r == 0) out[0] = (wsh[0] + wsh[1] + wsh[2] + wsh[3]) * (1.0f / 256.0f);
}

extern "C" void kernel_launch(void* const* d_in, const int* in_sizes, int n_in,
                              void* d_out, int out_size, void* d_ws, size_t ws_size,
                              hipStream_t stream) {
  const float* sim = (const float*)d_in[0];
  const float* label = (const float*)d_in[1];
  float* out = (float*)d_out;

  // workspace layout (floats): sp[1024] | sn[1024] | top[1024*16] | cnt[1024]
  constexpr int P = B * SPLIT;  // 1024 partials
  float* wsf = (float*)d_ws;
  float* ws_sp = wsf;
  float* ws_sn = wsf + P;
  float* ws_top = wsf + 2 * P;
  int* ws_cnt = (int*)(wsf + 2 * P + P * 16);

  ranking_partial_kernel<<<dim3(P), dim3(THREADS), 0, stream>>>(
      sim, label, ws_sp, ws_sn, ws_cnt, ws_top);
  combine_kernel<<<dim3(1), dim3(256), 0, stream>>>(ws_sp, ws_sn, ws_cnt, ws_top,
                                                    out);
}